// Round 1
// baseline (543.600 us; speedup 1.0000x reference)
//
#include <hip/hip_runtime.h>
#include <hip/hip_bf16.h>

#define N 2048
#define TILE 32
#define NT 64            // N / TILE
#define NPAIRS (NT*(NT+1)/2)   // 2080

// ws float offsets
#define OFF_ROWSUM 0
#define OFF_COLSUM 32768
#define OFF_DIAG   65536
#define OFF_SUMS   98304      // [0..15]=diagsum, [16..31]=totsum
#define OFF_A      98336
#define OFF_B      131104
#define OFF_D      163872
#define OFF_C      196640
#define OFF_COLPART 196656    // 64 slabs * 16 c * 2048
#define NSLAB 64

// ---------------- reduce: rowsum, diag, colpart, diagsum/totsum ----------------
__global__ __launch_bounds__(256) void reduce_kernel(const float* __restrict__ X,
                                                     float* __restrict__ ws) {
    const int c = blockIdx.y;
    const int slab = blockIdx.x;          // 64 slabs of 32 rows
    const int tid = threadIdx.x;
    const int wave = tid >> 6, lane = tid & 63;

    float* rowsum = ws + OFF_ROWSUM;
    float* diagv  = ws + OFF_DIAG;
    float* sums   = ws + OFF_SUMS;
    float* colpart = ws + OFF_COLPART + (size_t)slab * 16 * N + (size_t)c * N;

    __shared__ float colbuf[N];
    #pragma unroll
    for (int k = 0; k < 8; ++k) colbuf[tid + 256 * k] = 0.f;
    __syncthreads();

    float colacc[32];
    #pragma unroll
    for (int k = 0; k < 32; ++k) colacc[k] = 0.f;
    float dacc = 0.f, totacc = 0.f;

    const int row0 = slab * 32 + wave * 8;
    const float* Xc = X + (size_t)c * N * N;
    for (int r = 0; r < 8; ++r) {
        const int row = row0 + r;
        const float* rp = Xc + (size_t)row * N;
        float part = 0.f;
        #pragma unroll
        for (int k = 0; k < 32; ++k) {
            float v = rp[lane + 64 * k];
            part += v;
            colacc[k] += v;
            if (lane + 64 * k == row) { diagv[c * N + row] = v; dacc += v; }
        }
        #pragma unroll
        for (int s = 1; s < 64; s <<= 1) part += __shfl_xor(part, s);
        if (lane == 0) { rowsum[c * N + row] = part; totacc += part; }
    }
    #pragma unroll
    for (int s = 1; s < 64; s <<= 1) dacc += __shfl_xor(dacc, s);
    if (lane == 0) {
        atomicAdd(&sums[c], dacc);
        atomicAdd(&sums[16 + c], totacc);
    }
    __syncthreads();
    #pragma unroll
    for (int k = 0; k < 32; ++k) atomicAdd(&colbuf[lane + 64 * k], colacc[k]);
    __syncthreads();
    #pragma unroll
    for (int k = 0; k < 8; ++k) colpart[tid + 256 * k] = colbuf[tid + 256 * k];
}

// ---------------- colreduce: colsum[c][y] = sum over slabs ----------------
__global__ __launch_bounds__(256) void colreduce_kernel(float* __restrict__ ws) {
    const int c = blockIdx.y;
    const int y = blockIdx.x * 256 + threadIdx.x;
    const float* colpart = ws + OFF_COLPART;
    float s = 0.f;
    for (int sl = 0; sl < NSLAB; ++sl)
        s += colpart[(size_t)sl * 16 * N + (size_t)c * N + y];
    ws[OFF_COLSUM + c * N + y] = s;
}

// ---------------- fold: A, B, D, C ----------------
__global__ __launch_bounds__(256) void fold_kernel(const float* __restrict__ W,
                                                   const float* __restrict__ bias,
                                                   float* __restrict__ ws) {
    const int o = blockIdx.x;
    const int tid = threadIdx.x;
    const float invN = 1.f / (float)N;
    const float invN2 = invN * invN;
    const float* rowsum = ws + OFF_ROWSUM;
    const float* colsum = ws + OFF_COLSUM;
    const float* diagv  = ws + OFF_DIAG;
    const float* sums   = ws + OFF_SUMS;
    float* Abuf = ws + OFF_A;
    float* Bbuf = ws + OFF_B;
    float* Dbuf = ws + OFF_D;
    float* Cbuf = ws + OFF_C;

    if (tid == 0) {
        float cacc = 0.f;
        #pragma unroll
        for (int c = 0; c < 16; ++c)
            cacc += (sums[c] * invN) * W[11 * 256 + c * 16 + o]
                  + (sums[16 + c] * invN2) * W[14 * 256 + c * 16 + o];
        float sb = 0.f;
        for (int p = 0; p < 15; ++p) sb += bias[p];
        Cbuf[o] = cacc + sb;
    }

    // uniform part of D (diagmean, totmean terms)
    float du = 0.f;
    #pragma unroll
    for (int c = 0; c < 16; ++c)
        du += (sums[c] * invN) * W[2 * 256 + c * 16 + o]
            + (sums[16 + c] * invN2) * W[4 * 256 + c * 16 + o];

    for (int k = 0; k < 8; ++k) {
        const int x = tid + 256 * k;
        float a = 0.f, b = 0.f, d = 0.f;
        #pragma unroll
        for (int c = 0; c < 16; ++c) {
            const float dg = diagv[c * N + x];
            const float rm = rowsum[c * N + x] * invN;
            const float cm = colsum[c * N + x] * invN;
            a += dg * W[5 * 256 + c * 16 + o] + rm * W[12 * 256 + c * 16 + o] + cm * W[7 * 256 + c * 16 + o];
            b += dg * W[9 * 256 + c * 16 + o] + rm * W[13 * 256 + c * 16 + o] + cm * W[10 * 256 + c * 16 + o];
            d += dg * W[0 * 256 + c * 16 + o] + rm * W[3 * 256 + c * 16 + o]  + cm * W[1 * 256 + c * 16 + o];
        }
        Abuf[o * N + x] = a;
        Bbuf[o * N + x] = b;
        Dbuf[o * N + x] = d + du;
    }
}

// ---------------- main: tile-pair kernel ----------------
__global__ __launch_bounds__(512, 4) void main_kernel(const float* __restrict__ X,
                                                      const float* __restrict__ W,
                                                      const float* __restrict__ ws,
                                                      float* __restrict__ out) {
    // decode triangular pair (bx <= by)
    int rem = blockIdx.x, bx = 0;
    while (rem >= NT - bx) { rem -= NT - bx; ++bx; }
    const int by = bx + rem;
    const int x0 = bx * TILE, y0 = by * TILE;

    const int tid = threadIdx.x;
    const int side = tid >> 8;     // 0: tile-A pixels, 1: tile-B pixels (wave-uniform)
    const int t = tid & 255;

    __shared__ float lds[2][4][TILE][TILE + 1];

    const float* Abuf = ws + OFF_A;
    const float* Bbuf = ws + OFF_B;
    const float* Dbuf = ws + OFF_D;
    const float* Cbuf = ws + OFF_C;

    float acc[4][16];
    #pragma unroll
    for (int k = 0; k < 4; ++k)
        #pragma unroll
        for (int o = 0; o < 16; ++o) acc[k][o] = 0.f;

    // per-pixel LDS offsets (channel stride = 32*33)
    int doff[4], toff[4];
    #pragma unroll
    for (int k = 0; k < 4; ++k) {
        const int px = t + 256 * k;
        const int lx = px >> 5, ly = px & 31;
        doff[k] = lx * (TILE + 1) + ly;
        toff[k] = ly * (TILE + 1) + lx;
    }
    const float* dbase = &lds[side][0][0][0];
    const float* tbase = &lds[1 - side][0][0][0];

    for (int cc = 0; cc < 4; ++cc) {
        __syncthreads();
        // stage 4 channels of both tiles: 2048 float4 quads
        #pragma unroll
        for (int k = 0; k < 4; ++k) {
            const int q = tid + 512 * k;       // 0..2047
            const int tile = q >> 10;
            const int rrem = q & 1023;
            const int cl = rrem >> 8;
            const int e = rrem & 255;
            const int row = e >> 3;
            const int qc = e & 7;
            const int gr = (tile == 0) ? (x0 + row) : (y0 + row);
            const int gc = (tile == 0) ? (y0 + 4 * qc) : (x0 + 4 * qc);
            const float4 v = *(const float4*)(X + (size_t)(cc * 4 + cl) * N * N + (size_t)gr * N + gc);
            float* dst = &lds[tile][cl][row][4 * qc];
            dst[0] = v.x; dst[1] = v.y; dst[2] = v.z; dst[3] = v.w;
        }
        __syncthreads();

        #pragma unroll
        for (int cl = 0; cl < 4; ++cl) {
            const int c = cc * 4 + cl;
            float dval[4], tval[4];
            #pragma unroll
            for (int k = 0; k < 4; ++k) {
                dval[k] = dbase[cl * (TILE * (TILE + 1)) + doff[k]];
                tval[k] = tbase[cl * (TILE * (TILE + 1)) + toff[k]];
            }
            const float* wid = W + 8 * 256 + c * 16;  // identity partition
            const float* wtr = W + 6 * 256 + c * 16;  // transpose partition
            #pragma unroll
            for (int o = 0; o < 16; ++o) {
                const float wi = wid[o], wt = wtr[o];
                #pragma unroll
                for (int k = 0; k < 4; ++k) acc[k][o] += wi * dval[k] + wt * tval[k];
            }
        }
    }

    // epilogue
    #pragma unroll
    for (int k = 0; k < 4; ++k) {
        const int px = t + 256 * k;
        const int lx = px >> 5, ly = px & 31;
        const int x = (side == 0) ? (x0 + lx) : (y0 + lx);
        const int y = (side == 0) ? (y0 + ly) : (x0 + ly);
        #pragma unroll
        for (int o = 0; o < 16; ++o) {
            float v = acc[k][o] + Abuf[o * N + x] + Bbuf[o * N + y] + Cbuf[o];
            if (x == y) v += Dbuf[o * N + x];
            __builtin_nontemporal_store(v, &out[(size_t)o * N * N + (size_t)x * N + y]);
        }
    }
}

extern "C" void kernel_launch(void* const* d_in, const int* in_sizes, int n_in,
                              void* d_out, int out_size, void* d_ws, size_t ws_size,
                              hipStream_t stream) {
    (void)in_sizes; (void)n_in; (void)out_size; (void)ws_size;
    const float* X    = (const float*)d_in[0];
    const float* W    = (const float*)d_in[1];
    const float* bias = (const float*)d_in[2];
    float* out = (float*)d_out;
    float* ws  = (float*)d_ws;

    hipMemsetAsync(ws + OFF_SUMS, 0, 32 * sizeof(float), stream);
    reduce_kernel<<<dim3(NSLAB, 16), 256, 0, stream>>>(X, ws);
    colreduce_kernel<<<dim3(8, 16), 256, 0, stream>>>(ws);
    fold_kernel<<<16, 256, 0, stream>>>(W, bias, ws);
    main_kernel<<<NPAIRS, 512, 0, stream>>>(X, W, ws, out);
}